// Round 7
// baseline (445.349 us; speedup 1.0000x reference)
//
#include <hip/hip_runtime.h>
#include <hip/hip_bf16.h>

#define NNODES 100000
#define DIN    256
#define NHID   128
#define EPS    1e-5f
#define NB     ((NNODES + 255) >> 8)   // 391 buckets of 256 dst nodes
#define BCAP   4864                    // per-bucket capacity (mean 4092, +12 sigma)
#define BDEPTH 16                      // LDS ring depth per bucket (entries)
#define CURPAD 16                      // global counters padded to 64B
#define NBLK   128                     // bucket_kernel blocks

typedef __attribute__((ext_vector_type(8))) short short8v;  // 8 x bf16
typedef __attribute__((ext_vector_type(4))) float f32x4;

static __device__ __forceinline__ unsigned short f2bf(float v) {
    __hip_bfloat16 b = __float2bfloat16(v);
    return *reinterpret_cast<unsigned short*>(&b);
}
static __device__ __forceinline__ float bfhi2f(unsigned int u) {
    union { unsigned int i; float f; } x; x.i = u & 0xFFFF0000u; return x.f;
}
static __device__ __forceinline__ float bflo2f(unsigned int u) {
    union { unsigned int i; float f; } x; x.i = u << 16; return x.f;
}

// ---------------- W transpose to bf16: Wt[c][k] = bf16(W[k][c]) ----------------
__global__ __launch_bounds__(256) void wtrans_kernel(const float* __restrict__ W,
                                                     unsigned short* __restrict__ Wt, int K) {
    const int i = blockIdx.x * 256 + threadIdx.x;
    if (i < K * 128) {
        const int k = i >> 7, c = i & 127;
        Wt[c * K + k] = f2bf(W[i]);
    }
}

// ---------------- MFMA GEMM: C[M][128] = A[M][K] @ W[K][128], no big LDS ----------------
// B-fragments load directly from global pre-transposed bf16 Wtb (L1/L2-resident).
// MODE 0: A fp32 -> bf16 (layer 1). MODE 1: fused BN(scale/shift)+ReLU (layer 2).
template <int K, int MODE>
__global__ __launch_bounds__(256) void mfma_gemm(const float* __restrict__ Af,
                                                 const unsigned short* __restrict__ Wtb,
                                                 const float* __restrict__ SS,
                                                 unsigned short* __restrict__ C, int M) {
    __shared__ float ssl[256];
    const int t = threadIdx.x;
    if (MODE == 1) {
        if (t < 256) ssl[t] = SS[t];
        __syncthreads();
    }

    const int wid = t >> 6;
    const int lane = t & 63;
    const int wr = wid >> 1, wc = wid & 1;
    const int l15 = lane & 15, g = lane >> 4;
    const int R0 = blockIdx.x * 128 + wr * 64;

    f32x4 acc[4][4] = {};

    for (int s = 0; s < K / 32; ++s) {
        short8v b[4];
#pragma unroll
        for (int n = 0; n < 4; ++n) {
            const int col = wc * 64 + n * 16 + l15;
            b[n] = *reinterpret_cast<const short8v*>(&Wtb[(size_t)col * K + s * 32 + g * 8]);
        }
        float sc[8], sh[8];
        if (MODE == 1) {
#pragma unroll
            for (int j = 0; j < 8; ++j) {
                sc[j] = ssl[s * 32 + g * 8 + j];
                sh[j] = ssl[128 + s * 32 + g * 8 + j];
            }
        }
        short8v a[4];
#pragma unroll
        for (int m = 0; m < 4; ++m) {
            int row = R0 + m * 16 + l15;
            row = row < M ? row : M - 1;   // clamp; pad rows discarded at store
            const float* p = Af + (size_t)row * K + s * 32 + g * 8;
            const float4 v0 = *reinterpret_cast<const float4*>(p);
            const float4 v1 = *reinterpret_cast<const float4*>(p + 4);
            float vv[8] = {v0.x, v0.y, v0.z, v0.w, v1.x, v1.y, v1.z, v1.w};
            short8v av;
#pragma unroll
            for (int j = 0; j < 8; ++j) {
                float y = vv[j];
                if (MODE == 1) y = fmaxf(fmaf(y, sc[j], sh[j]), 0.f);
                av[j] = (short)f2bf(y);
            }
            a[m] = av;
        }
#pragma unroll
        for (int m = 0; m < 4; ++m)
#pragma unroll
            for (int n = 0; n < 4; ++n)
                acc[m][n] = __builtin_amdgcn_mfma_f32_16x16x32_bf16(a[m], b[n], acc[m][n], 0, 0, 0);
    }

    // C/D layout: col = lane&15, row = (lane>>4)*4 + q
#pragma unroll
    for (int m = 0; m < 4; ++m) {
#pragma unroll
        for (int q = 0; q < 4; ++q) {
            const int row = R0 + m * 16 + g * 4 + q;
            if (row < M) {
                unsigned short* cp = C + (size_t)row * NHID + wc * 64 + l15;
#pragma unroll
                for (int n = 0; n < 4; ++n)
                    cp[n * 16] = f2bf(acc[m][n][q]);
            }
        }
    }
}

// ---------------- Pass A: bucket edges via LDS ring buffers, full 64B line flushes ----------------
__global__ __launch_bounds__(256) void bucket_kernel(const int* __restrict__ src,
                                                     const int* __restrict__ dst,
                                                     const float* __restrict__ w,
                                                     int* __restrict__ gcur,
                                                     int2* __restrict__ bstage,
                                                     int E, int EPB) {
    __shared__ int2 buf[NB][BDEPTH];   // ~50 KB ring buffers
    __shared__ int lcur[NB];           // appended (monotonic)
    __shared__ int lflu[NB];           // flushed  (monotonic, multiple of 8)
    const int t = threadIdx.x;
    for (int i = t; i < NB; i += 256) { lcur[i] = 0; lflu[i] = 0; }
    __syncthreads();

    const int e0 = blockIdx.x * EPB;
    const int e1 = min(E, e0 + EPB);

    for (int p = e0; p < e1; p += 256) {
        const int e = p + t;
        int spill_b = -1;
        int2 pay;
        if (e < e1) {
            const int d = dst[e];
            const int b = d >> 8;
            pay.x = src[e] | ((d & 255) << 17);   // src < 2^17, dst low 8 in [17..24]
            pay.y = __float_as_int(w[e]);
            const int pos = atomicAdd(&lcur[b], 1);
            if (pos - lflu[b] < BDEPTH) {          // lflu stable within phase
                buf[b][pos & (BDEPTH - 1)] = pay;
            } else {
                spill_b = b;                        // rare ring overflow
            }
        }
        if (spill_b >= 0) {
            const int gp = atomicAdd(&gcur[spill_b * CURPAD], 1);
            if (gp < BCAP) bstage[(size_t)spill_b * BCAP + gp] = pay;
        }
        __syncthreads();
        // flush all full 8-entry (64B) groups
        for (int bb = t; bb < NB; bb += 256) {
            int have = lcur[bb] - lflu[bb];
            while (have >= 8) {
                const int h = lflu[bb] & (BDEPTH - 1);   // 0 or 8
                const int gp = atomicAdd(&gcur[bb * CURPAD], 8);
                if (gp + 8 <= BCAP) {
                    int4* d4 = reinterpret_cast<int4*>(&bstage[(size_t)bb * BCAP + gp]);
                    const int4* s4 = reinterpret_cast<const int4*>(&buf[bb][h]);
                    d4[0] = s4[0]; d4[1] = s4[1]; d4[2] = s4[2]; d4[3] = s4[3];
                }
                lflu[bb] += 8;
                have -= 8;
            }
        }
        __syncthreads();
    }
    // drain leftovers (<8 per bucket)
    for (int bb = t; bb < NB; bb += 256) {
        const int have = lcur[bb] - lflu[bb];
        if (have > 0) {
            const int gp = atomicAdd(&gcur[bb * CURPAD], have);
            for (int i = 0; i < have; ++i) {
                const int p2 = gp + i;
                if (p2 < BCAP)
                    bstage[(size_t)bb * BCAP + p2] = buf[bb][(lflu[bb] + i) & (BDEPTH - 1)];
            }
        }
    }
}

// ---------------- Pass B: per-bucket exact CSR via LDS hist/scan/cursors ----------------
__global__ __launch_bounds__(256) void csr_kernel(const int* __restrict__ gcur,
                                                  const int2* __restrict__ bstage,
                                                  int2* __restrict__ row_be,
                                                  int2* __restrict__ s_iw) {
    const int b = blockIdx.x;
    const int t = threadIdx.x;
    int cnt = gcur[b * CURPAD];
    if (cnt > BCAP) cnt = BCAP;
    const int sbase = b * BCAP;

    __shared__ int hist[256], scn[256], cur[256];
    hist[t] = 0;
    __syncthreads();
    for (int i = t; i < cnt; i += 256)
        atomicAdd(&hist[(bstage[sbase + i].x >> 17) & 255], 1);
    __syncthreads();
    scn[t] = hist[t];
    __syncthreads();
    for (int off = 1; off < 256; off <<= 1) {
        const int v = (t >= off) ? scn[t - off] : 0;
        __syncthreads();
        scn[t] += v;
        __syncthreads();
    }
    const int excl = scn[t] - hist[t];
    const int d = b * 256 + t;
    if (d < NNODES) {
        int2 be;
        be.x = sbase + excl;
        be.y = sbase + scn[t];
        row_be[d] = be;
    }
    cur[t] = excl;
    __syncthreads();
    for (int i = t; i < cnt; i += 256) {
        const int2 e = bstage[sbase + i];
        const int l = (e.x >> 17) & 255;
        const int p = atomicAdd(&cur[l], 1);
        int2 o;
        o.x = e.x & 0x1FFFF;
        o.y = e.y;
        s_iw[sbase + p] = o;
    }
}

// ---------------- Aggregate: one wave per node, bf16 gather, fp32 accumulate ----------------
__global__ __launch_bounds__(256) void aggregate_kernel(const unsigned short* __restrict__ hb,
                                                        const int2* __restrict__ row_be,
                                                        const int2* __restrict__ s_iw,
                                                        float* __restrict__ out, int n) {
    const int wid = (blockIdx.x * 256 + threadIdx.x) >> 6;
    if (wid >= n) return;
    const int lane = threadIdx.x & 63;
    const int2 be = row_be[wid];
    const int beg = be.x, end = be.y;
    const int boff = lane * 2;

    float ax = 0.f, ay = 0.f;
    int j = beg;
    for (; j + 4 <= end; j += 4) {
        const int2 e0 = s_iw[j], e1 = s_iw[j + 1], e2 = s_iw[j + 2], e3 = s_iw[j + 3];
        const unsigned int v0 = *reinterpret_cast<const unsigned int*>(hb + (size_t)e0.x * NHID + boff);
        const unsigned int v1 = *reinterpret_cast<const unsigned int*>(hb + (size_t)e1.x * NHID + boff);
        const unsigned int v2 = *reinterpret_cast<const unsigned int*>(hb + (size_t)e2.x * NHID + boff);
        const unsigned int v3 = *reinterpret_cast<const unsigned int*>(hb + (size_t)e3.x * NHID + boff);
        const float w0 = __int_as_float(e0.y), w1 = __int_as_float(e1.y);
        const float w2 = __int_as_float(e2.y), w3 = __int_as_float(e3.y);
        ax = fmaf(w0, bflo2f(v0), ax); ay = fmaf(w0, bfhi2f(v0), ay);
        ax = fmaf(w1, bflo2f(v1), ax); ay = fmaf(w1, bfhi2f(v1), ay);
        ax = fmaf(w2, bflo2f(v2), ax); ay = fmaf(w2, bfhi2f(v2), ay);
        ax = fmaf(w3, bflo2f(v3), ax); ay = fmaf(w3, bfhi2f(v3), ay);
    }
    for (; j < end; ++j) {
        const int2 e0 = s_iw[j];
        const unsigned int v0 = *reinterpret_cast<const unsigned int*>(hb + (size_t)e0.x * NHID + boff);
        const float w0 = __int_as_float(e0.y);
        ax = fmaf(w0, bflo2f(v0), ax);
        ay = fmaf(w0, bfhi2f(v0), ay);
    }
    float2 r;
    r.x = ax;
    r.y = ay;
    *reinterpret_cast<float2*>(out + (size_t)wid * NHID + boff) = r;
}

// ---------------- BN stats / finalize / final apply ----------------
__global__ __launch_bounds__(256) void stats_kernel(const float* __restrict__ h,
                                                    float* __restrict__ sums, int nrows) {
    const int col = threadIdx.x & 127;
    const int half = threadIdx.x >> 7;
    float s = 0.f, sq = 0.f;
    for (int r = blockIdx.x * 2 + half; r < nrows; r += gridDim.x * 2) {
        const float v = h[(size_t)r * NHID + col];
        s += v;
        sq += v * v;
    }
    __shared__ float ls[256], lq[256];
    ls[threadIdx.x] = s;
    lq[threadIdx.x] = sq;
    __syncthreads();
    if (threadIdx.x < 128) {
        atomicAdd(&sums[col], ls[threadIdx.x] + ls[threadIdx.x + 128]);
        atomicAdd(&sums[128 + col], lq[threadIdx.x] + lq[threadIdx.x + 128]);
    }
}

__global__ void finalize_kernel(const float* __restrict__ sums,
                                const float* __restrict__ gamma,
                                const float* __restrict__ beta,
                                float* __restrict__ ss) {
    const int c = threadIdx.x;
    const float invN = 1.0f / (float)NNODES;
    const float mean = sums[c] * invN;
    const float var = sums[128 + c] * invN - mean * mean;
    const float scale = gamma[c] * rsqrtf(var + EPS);
    ss[c] = scale;
    ss[128 + c] = beta[c] - mean * scale;
}

__global__ __launch_bounds__(256) void apply_f32_kernel(const float* __restrict__ in,
                                                        const float* __restrict__ ss,
                                                        float* __restrict__ out, int n4) {
    const int idx = blockIdx.x * 256 + threadIdx.x;
    if (idx >= n4) return;
    const int c = (idx & 31) * 4;
    const float4 v = reinterpret_cast<const float4*>(in)[idx];
    const float4 sc = *reinterpret_cast<const float4*>(ss + c);
    const float4 sh = *reinterpret_cast<const float4*>(ss + 128 + c);
    float4 r;
    r.x = fmaxf(fmaf(v.x, sc.x, sh.x), 0.f);
    r.y = fmaxf(fmaf(v.y, sc.y, sh.y), 0.f);
    r.z = fmaxf(fmaf(v.z, sc.z, sh.z), 0.f);
    r.w = fmaxf(fmaf(v.w, sc.w, sh.w), 0.f);
    reinterpret_cast<float4*>(out)[idx] = r;
}

extern "C" void kernel_launch(void* const* d_in, const int* in_sizes, int n_in,
                              void* d_out, int out_size, void* d_ws, size_t ws_size,
                              hipStream_t stream) {
    const float* x   = (const float*)d_in[0];
    const int*   ei  = (const int*)d_in[1];
    const float* ew  = (const float*)d_in[2];
    const float* W1  = (const float*)d_in[3];
    const float* g1  = (const float*)d_in[5];
    const float* be1 = (const float*)d_in[6];
    const float* W2  = (const float*)d_in[7];
    const float* g2  = (const float*)d_in[9];
    const float* be2 = (const float*)d_in[10];
    float* out = (float*)d_out;

    const int M = NNODES;
    const int E = in_sizes[2];
    const int* src = ei;
    const int* dst = ei + E;

    // workspace layout (~108 MB)
    unsigned short* hb = (unsigned short*)d_ws;               // M*128 bf16 (25.6 MB)
    float* agg   = (float*)(hb + (size_t)M * NHID);           // M*128 fp32 (51.2 MB)
    int2* bstage = (int2*)(agg + (size_t)M * NHID);           // NB*BCAP (15.2 MB)
    int2* s_iw   = bstage + (size_t)NB * BCAP;                // NB*BCAP (15.2 MB)
    int2* row_be = s_iw + (size_t)NB * BCAP;                  // N (800 KB)
    int* gcur    = (int*)(row_be + NNODES);                   // NB*CURPAD (25 KB)
    unsigned short* Wt1b = (unsigned short*)(gcur + NB * CURPAD);  // 256*128 bf16 (64 KB)
    unsigned short* Wt2b = Wt1b + DIN * NHID;                 // 128*128 bf16 (32 KB)
    float* sums  = (float*)(Wt2b + NHID * NHID);              // 256
    float* ss    = sums + 256;                                // 256

    const int gemm_grid = (M + 127) / 128;
    const int n4 = M * NHID / 4;
    const int app_grid = (n4 + 255) / 256;
    const int agg_grid = (M * 64 + 255) / 256;
    const int EPB = (E + NBLK - 1) / NBLK;

    // ---- Prep: W transposes + CSR build (shared by both layers) ----
    wtrans_kernel<<<(DIN * NHID + 255) / 256, 256, 0, stream>>>(W1, Wt1b, DIN);
    wtrans_kernel<<<(NHID * NHID + 255) / 256, 256, 0, stream>>>(W2, Wt2b, NHID);
    hipMemsetAsync(gcur, 0, (size_t)NB * CURPAD * sizeof(int), stream);
    bucket_kernel<<<NBLK, 256, 0, stream>>>(src, dst, ew, gcur, bstage, E, EPB);
    csr_kernel<<<NB, 256, 0, stream>>>(gcur, bstage, row_be, s_iw);

    // ---- Layer 1 ----
    mfma_gemm<DIN, 0><<<gemm_grid, 256, 0, stream>>>(x, Wt1b, nullptr, hb, M);
    aggregate_kernel<<<agg_grid, 256, 0, stream>>>(hb, row_be, s_iw, agg, M);
    hipMemsetAsync(sums, 0, 256 * sizeof(float), stream);
    stats_kernel<<<1024, 256, 0, stream>>>(agg, sums, M);
    finalize_kernel<<<1, 128, 0, stream>>>(sums, g1, be1, ss);

    // ---- Layer 2 (BN1+ReLU fused into GEMM2's A-load) ----
    mfma_gemm<NHID, 1><<<gemm_grid, 256, 0, stream>>>(agg, Wt2b, ss, hb, M);
    aggregate_kernel<<<agg_grid, 256, 0, stream>>>(hb, row_be, s_iw, agg, M);
    hipMemsetAsync(sums, 0, 256 * sizeof(float), stream);
    stats_kernel<<<1024, 256, 0, stream>>>(agg, sums, M);
    finalize_kernel<<<1, 128, 0, stream>>>(sums, g2, be2, ss);
    apply_f32_kernel<<<app_grid, 256, 0, stream>>>(agg, ss, out, n4);
}

// Round 8
// 399.268 us; speedup vs baseline: 1.1154x; 1.1154x over previous
//
#include <hip/hip_runtime.h>
#include <hip/hip_bf16.h>

#define NNODES 100000
#define DIN    256
#define NHID   128
#define EPS    1e-5f
#define SHIFT  10
#define NB2    ((NNODES + 1023) >> SHIFT)   // 98 buckets of 1024 dst
#define BCAP2  17408                        // mean 16327 + ~8.5 sigma, mult of 8
#define CURPAD 16                           // global counters padded to 64B
#define PH     2048                         // edges per partition phase

typedef __attribute__((ext_vector_type(8))) short short8v;  // 8 x bf16
typedef __attribute__((ext_vector_type(4))) float f32x4;

static __device__ __forceinline__ unsigned short f2bf(float v) {
    __hip_bfloat16 b = __float2bfloat16(v);
    return *reinterpret_cast<unsigned short*>(&b);
}
static __device__ __forceinline__ float bfhi2f(unsigned int u) {
    union { unsigned int i; float f; } x; x.i = u & 0xFFFF0000u; return x.f;
}
static __device__ __forceinline__ float bflo2f(unsigned int u) {
    union { unsigned int i; float f; } x; x.i = u << 16; return x.f;
}

// ---------------- W transpose to bf16: Wt[c][k] = bf16(W[k][c]) ----------------
__global__ __launch_bounds__(256) void wtrans_kernel(const float* __restrict__ W,
                                                     unsigned short* __restrict__ Wt, int K) {
    const int i = blockIdx.x * 256 + threadIdx.x;
    if (i < K * 128) {
        const int k = i >> 7, c = i & 127;
        Wt[c * K + k] = f2bf(W[i]);
    }
}

// ---------------- MFMA GEMM: C[M][128] = A[M][K] @ W[K][128], no big LDS ----------------
// B-fragments load directly from global pre-transposed bf16 Wtb (L1/L2-resident).
// MODE 0: A fp32 -> bf16 (layer 1). MODE 1: fused BN(scale/shift)+ReLU (layer 2).
template <int K, int MODE>
__global__ __launch_bounds__(256) void mfma_gemm(const float* __restrict__ Af,
                                                 const unsigned short* __restrict__ Wtb,
                                                 const float* __restrict__ SS,
                                                 unsigned short* __restrict__ C, int M) {
    __shared__ float ssl[256];
    const int t = threadIdx.x;
    if (MODE == 1) {
        if (t < 256) ssl[t] = SS[t];
        __syncthreads();
    }

    const int wid = t >> 6;
    const int lane = t & 63;
    const int wr = wid >> 1, wc = wid & 1;
    const int l15 = lane & 15, g = lane >> 4;
    const int R0 = blockIdx.x * 128 + wr * 64;

    f32x4 acc[4][4] = {};

    for (int s = 0; s < K / 32; ++s) {
        short8v b[4];
#pragma unroll
        for (int n = 0; n < 4; ++n) {
            const int col = wc * 64 + n * 16 + l15;
            b[n] = *reinterpret_cast<const short8v*>(&Wtb[(size_t)col * K + s * 32 + g * 8]);
        }
        float sc[8], sh[8];
        if (MODE == 1) {
#pragma unroll
            for (int j = 0; j < 8; ++j) {
                sc[j] = ssl[s * 32 + g * 8 + j];
                sh[j] = ssl[128 + s * 32 + g * 8 + j];
            }
        }
        short8v a[4];
#pragma unroll
        for (int m = 0; m < 4; ++m) {
            int row = R0 + m * 16 + l15;
            row = row < M ? row : M - 1;   // clamp; pad rows discarded at store
            const float* p = Af + (size_t)row * K + s * 32 + g * 8;
            const float4 v0 = *reinterpret_cast<const float4*>(p);
            const float4 v1 = *reinterpret_cast<const float4*>(p + 4);
            float vv[8] = {v0.x, v0.y, v0.z, v0.w, v1.x, v1.y, v1.z, v1.w};
            short8v av;
#pragma unroll
            for (int j = 0; j < 8; ++j) {
                float y = vv[j];
                if (MODE == 1) y = fmaxf(fmaf(y, sc[j], sh[j]), 0.f);
                av[j] = (short)f2bf(y);
            }
            a[m] = av;
        }
#pragma unroll
        for (int m = 0; m < 4; ++m)
#pragma unroll
            for (int n = 0; n < 4; ++n)
                acc[m][n] = __builtin_amdgcn_mfma_f32_16x16x32_bf16(a[m], b[n], acc[m][n], 0, 0, 0);
    }

    // C/D layout: col = lane&15, row = (lane>>4)*4 + q
#pragma unroll
    for (int m = 0; m < 4; ++m) {
#pragma unroll
        for (int q = 0; q < 4; ++q) {
            const int row = R0 + m * 16 + g * 4 + q;
            if (row < M) {
                unsigned short* cp = C + (size_t)row * NHID + wc * 64 + l15;
#pragma unroll
                for (int n = 0; n < 4; ++n)
                    cp[n * 16] = f2bf(acc[m][n][q]);
            }
        }
    }
}

// ---------------- Pass A: phase-sorted partition into 98 buckets ----------------
// Per 2048-edge phase: LDS hist -> scan -> bucket-grouped LDS staging -> one global
// cursor claim per bucket -> coalesced run writes (avg run ~21 entries = full lines).
__global__ __launch_bounds__(256) void part_kernel(const int* __restrict__ src,
                                                   const int* __restrict__ dst,
                                                   const float* __restrict__ w,
                                                   int* __restrict__ gcur,
                                                   int2* __restrict__ bstage, int E) {
    __shared__ int2 staged[PH];
    __shared__ unsigned char aux[PH];
    __shared__ int hist[NB2], scn[NB2], cur[NB2], gbase[NB2];
    __shared__ int part[256];

    const int t = threadIdx.x;
    const int nchunk = (E + PH - 1) / PH;
    for (int c = blockIdx.x; c < nchunk; c += gridDim.x) {
        const int e0 = c * PH;
        const int cnt = min(PH, E - e0);
        for (int i = t; i < NB2; i += 256) hist[i] = 0;
        __syncthreads();

        int2 pay[8];
        int bk[8];
#pragma unroll
        for (int j = 0; j < 8; ++j) {
            const int i = j * 256 + t;
            bk[j] = -1;
            if (i < cnt) {
                const int e = e0 + i;
                const int d = dst[e];
                bk[j] = d >> SHIFT;
                pay[j].x = src[e] | ((d & 1023) << 17);   // src < 2^17, dst low10 in [17..26]
                pay[j].y = __float_as_int(w[e]);
                atomicAdd(&hist[bk[j]], 1);
            }
        }
        __syncthreads();

        // exclusive scan over NB2 bins (Hillis-Steele on 256 padded)
        part[t] = (t < NB2) ? hist[t] : 0;
        __syncthreads();
        for (int off = 1; off < 256; off <<= 1) {
            const int v = (t >= off) ? part[t - off] : 0;
            __syncthreads();
            part[t] += v;
            __syncthreads();
        }
        if (t < NB2) {
            const int ex = part[t] - hist[t];
            scn[t] = ex;
            cur[t] = ex;
        }
        __syncthreads();

        // scatter into bucket-grouped LDS staging
#pragma unroll
        for (int j = 0; j < 8; ++j) {
            if (bk[j] >= 0) {
                const int p = atomicAdd(&cur[bk[j]], 1);
                staged[p] = pay[j];
                aux[p] = (unsigned char)bk[j];
            }
        }
        // claim global space (one atomic per non-empty bucket)
        if (t < NB2 && hist[t] > 0) gbase[t] = atomicAdd(&gcur[t * CURPAD], hist[t]);
        __syncthreads();

        // coalesced run writes
        for (int i = t; i < cnt; i += 256) {
            const int b = aux[i];
            const int p = gbase[b] + (i - scn[b]);
            if (p < BCAP2) bstage[(size_t)b * BCAP2 + p] = staged[i];
        }
        __syncthreads();
    }
}

// ---------------- Pass B: per-bucket exact CSR (1024 bins) ----------------
__global__ __launch_bounds__(256) void csr_kernel(const int* __restrict__ gcur,
                                                  const int2* __restrict__ bstage,
                                                  int2* __restrict__ row_be,
                                                  int2* __restrict__ s_iw) {
    const int b = blockIdx.x;
    const int t = threadIdx.x;
    int cnt = gcur[b * CURPAD];
    if (cnt > BCAP2) cnt = BCAP2;
    const int sbase = b * BCAP2;

    __shared__ int hist[1024], scn[1024], cur[1024];
    __shared__ int part[256];
    for (int i = t; i < 1024; i += 256) hist[i] = 0;
    __syncthreads();
    for (int i = t; i < cnt; i += 256)
        atomicAdd(&hist[(bstage[sbase + i].x >> 17) & 1023], 1);
    __syncthreads();

    // scan 1024 bins: thread t owns bins 4t..4t+3
    int loc[4];
    int s0 = 0;
#pragma unroll
    for (int j = 0; j < 4; ++j) { loc[j] = hist[t * 4 + j]; s0 += loc[j]; }
    part[t] = s0;
    __syncthreads();
    for (int off = 1; off < 256; off <<= 1) {
        const int v = (t >= off) ? part[t - off] : 0;
        __syncthreads();
        part[t] += v;
        __syncthreads();
    }
    int run = part[t] - s0;
#pragma unroll
    for (int j = 0; j < 4; ++j) {
        const int lb = t * 4 + j;
        scn[lb] = run;
        cur[lb] = run;
        const int d = (b << SHIFT) + lb;
        if (d < NNODES) {
            int2 be;
            be.x = sbase + run;
            be.y = sbase + run + loc[j];
            row_be[d] = be;
        }
        run += loc[j];
    }
    __syncthreads();

    for (int i = t; i < cnt; i += 256) {
        const int2 e = bstage[sbase + i];
        const int l = (e.x >> 17) & 1023;
        const int p = atomicAdd(&cur[l], 1);
        int2 o;
        o.x = e.x & 0x1FFFF;
        o.y = e.y;
        s_iw[sbase + p] = o;
    }
}

// ---------------- Aggregate: one wave per node, bf16 gather, fp32 accumulate ----------------
__global__ __launch_bounds__(256) void aggregate_kernel(const unsigned short* __restrict__ hb,
                                                        const int2* __restrict__ row_be,
                                                        const int2* __restrict__ s_iw,
                                                        float* __restrict__ out, int n) {
    const int wid = (blockIdx.x * 256 + threadIdx.x) >> 6;
    if (wid >= n) return;
    const int lane = threadIdx.x & 63;
    const int2 be = row_be[wid];
    const int beg = be.x, end = be.y;
    const int boff = lane * 2;

    float ax = 0.f, ay = 0.f;
    int j = beg;
    for (; j + 4 <= end; j += 4) {
        const int2 e0 = s_iw[j], e1 = s_iw[j + 1], e2 = s_iw[j + 2], e3 = s_iw[j + 3];
        const unsigned int v0 = *reinterpret_cast<const unsigned int*>(hb + (size_t)e0.x * NHID + boff);
        const unsigned int v1 = *reinterpret_cast<const unsigned int*>(hb + (size_t)e1.x * NHID + boff);
        const unsigned int v2 = *reinterpret_cast<const unsigned int*>(hb + (size_t)e2.x * NHID + boff);
        const unsigned int v3 = *reinterpret_cast<const unsigned int*>(hb + (size_t)e3.x * NHID + boff);
        const float w0 = __int_as_float(e0.y), w1 = __int_as_float(e1.y);
        const float w2 = __int_as_float(e2.y), w3 = __int_as_float(e3.y);
        ax = fmaf(w0, bflo2f(v0), ax); ay = fmaf(w0, bfhi2f(v0), ay);
        ax = fmaf(w1, bflo2f(v1), ax); ay = fmaf(w1, bfhi2f(v1), ay);
        ax = fmaf(w2, bflo2f(v2), ax); ay = fmaf(w2, bfhi2f(v2), ay);
        ax = fmaf(w3, bflo2f(v3), ax); ay = fmaf(w3, bfhi2f(v3), ay);
    }
    for (; j < end; ++j) {
        const int2 e0 = s_iw[j];
        const unsigned int v0 = *reinterpret_cast<const unsigned int*>(hb + (size_t)e0.x * NHID + boff);
        const float w0 = __int_as_float(e0.y);
        ax = fmaf(w0, bflo2f(v0), ax);
        ay = fmaf(w0, bfhi2f(v0), ay);
    }
    float2 r;
    r.x = ax;
    r.y = ay;
    *reinterpret_cast<float2*>(out + (size_t)wid * NHID + boff) = r;
}

// ---------------- BN stats / finalize / final apply ----------------
__global__ __launch_bounds__(256) void stats_kernel(const float* __restrict__ h,
                                                    float* __restrict__ sums, int nrows) {
    const int col = threadIdx.x & 127;
    const int half = threadIdx.x >> 7;
    float s = 0.f, sq = 0.f;
    for (int r = blockIdx.x * 2 + half; r < nrows; r += gridDim.x * 2) {
        const float v = h[(size_t)r * NHID + col];
        s += v;
        sq += v * v;
    }
    __shared__ float ls[256], lq[256];
    ls[threadIdx.x] = s;
    lq[threadIdx.x] = sq;
    __syncthreads();
    if (threadIdx.x < 128) {
        atomicAdd(&sums[col], ls[threadIdx.x] + ls[threadIdx.x + 128]);
        atomicAdd(&sums[128 + col], lq[threadIdx.x] + lq[threadIdx.x + 128]);
    }
}

__global__ void finalize_kernel(const float* __restrict__ sums,
                                const float* __restrict__ gamma,
                                const float* __restrict__ beta,
                                float* __restrict__ ss) {
    const int c = threadIdx.x;
    const float invN = 1.0f / (float)NNODES;
    const float mean = sums[c] * invN;
    const float var = sums[128 + c] * invN - mean * mean;
    const float scale = gamma[c] * rsqrtf(var + EPS);
    ss[c] = scale;
    ss[128 + c] = beta[c] - mean * scale;
}

__global__ __launch_bounds__(256) void apply_f32_kernel(const float* __restrict__ in,
                                                        const float* __restrict__ ss,
                                                        float* __restrict__ out, int n4) {
    const int idx = blockIdx.x * 256 + threadIdx.x;
    if (idx >= n4) return;
    const int c = (idx & 31) * 4;
    const float4 v = reinterpret_cast<const float4*>(in)[idx];
    const float4 sc = *reinterpret_cast<const float4*>(ss + c);
    const float4 sh = *reinterpret_cast<const float4*>(ss + 128 + c);
    float4 r;
    r.x = fmaxf(fmaf(v.x, sc.x, sh.x), 0.f);
    r.y = fmaxf(fmaf(v.y, sc.y, sh.y), 0.f);
    r.z = fmaxf(fmaf(v.z, sc.z, sh.z), 0.f);
    r.w = fmaxf(fmaf(v.w, sc.w, sh.w), 0.f);
    reinterpret_cast<float4*>(out)[idx] = r;
}

extern "C" void kernel_launch(void* const* d_in, const int* in_sizes, int n_in,
                              void* d_out, int out_size, void* d_ws, size_t ws_size,
                              hipStream_t stream) {
    const float* x   = (const float*)d_in[0];
    const int*   ei  = (const int*)d_in[1];
    const float* ew  = (const float*)d_in[2];
    const float* W1  = (const float*)d_in[3];
    const float* g1  = (const float*)d_in[5];
    const float* be1 = (const float*)d_in[6];
    const float* W2  = (const float*)d_in[7];
    const float* g2  = (const float*)d_in[9];
    const float* be2 = (const float*)d_in[10];
    float* out = (float*)d_out;

    const int M = NNODES;
    const int E = in_sizes[2];
    const int* src = ei;
    const int* dst = ei + E;

    // workspace layout (~105 MB)
    unsigned short* hb = (unsigned short*)d_ws;               // M*128 bf16 (25.6 MB)
    float* agg   = (float*)(hb + (size_t)M * NHID);           // M*128 fp32 (51.2 MB)
    int2* bstage = (int2*)(agg + (size_t)M * NHID);           // NB2*BCAP2 (13.65 MB)
    int2* s_iw   = bstage + (size_t)NB2 * BCAP2;              // NB2*BCAP2 (13.65 MB)
    int2* row_be = s_iw + (size_t)NB2 * BCAP2;                // N (800 KB)
    int* gcur    = (int*)(row_be + NNODES);                   // NB2*CURPAD (6.3 KB)
    unsigned short* Wt1b = (unsigned short*)(gcur + NB2 * CURPAD);  // 256*128 bf16
    unsigned short* Wt2b = Wt1b + DIN * NHID;                 // 128*128 bf16
    float* sums  = (float*)(Wt2b + NHID * NHID);              // 256
    float* ss    = sums + 256;                                // 256

    const int gemm_grid = (M + 127) / 128;
    const int n4 = M * NHID / 4;
    const int app_grid = (n4 + 255) / 256;
    const int agg_grid = (M * 64 + 255) / 256;
    const int part_grid = (E + PH - 1) / PH;

    // ---- Prep: W transposes + CSR build (shared by both layers) ----
    wtrans_kernel<<<(DIN * NHID + 255) / 256, 256, 0, stream>>>(W1, Wt1b, DIN);
    wtrans_kernel<<<(NHID * NHID + 255) / 256, 256, 0, stream>>>(W2, Wt2b, NHID);
    hipMemsetAsync(gcur, 0, (size_t)NB2 * CURPAD * sizeof(int), stream);
    part_kernel<<<part_grid, 256, 0, stream>>>(src, dst, ew, gcur, bstage, E);
    csr_kernel<<<NB2, 256, 0, stream>>>(gcur, bstage, row_be, s_iw);

    // ---- Layer 1 ----
    mfma_gemm<DIN, 0><<<gemm_grid, 256, 0, stream>>>(x, Wt1b, nullptr, hb, M);
    aggregate_kernel<<<agg_grid, 256, 0, stream>>>(hb, row_be, s_iw, agg, M);
    hipMemsetAsync(sums, 0, 256 * sizeof(float), stream);
    stats_kernel<<<1024, 256, 0, stream>>>(agg, sums, M);
    finalize_kernel<<<1, 128, 0, stream>>>(sums, g1, be1, ss);

    // ---- Layer 2 (BN1+ReLU fused into GEMM2's A-load) ----
    mfma_gemm<NHID, 1><<<gemm_grid, 256, 0, stream>>>(agg, Wt2b, ss, hb, M);
    aggregate_kernel<<<agg_grid, 256, 0, stream>>>(hb, row_be, s_iw, agg, M);
    hipMemsetAsync(sums, 0, 256 * sizeof(float), stream);
    stats_kernel<<<1024, 256, 0, stream>>>(agg, sums, M);
    finalize_kernel<<<1, 128, 0, stream>>>(sums, g2, be2, ss);
    apply_f32_kernel<<<app_grid, 256, 0, stream>>>(agg, ss, out, n4);
}

// Round 9
// 362.971 us; speedup vs baseline: 1.2270x; 1.1000x over previous
//
#include <hip/hip_runtime.h>
#include <hip/hip_bf16.h>

#define NNODES 100000
#define DIN    256
#define NHID   128
#define EPS    1e-5f
#define SHIFT  9
#define NB2    ((NNODES + 511) >> SHIFT)    // 196 buckets of 512 dst
#define BCAP2  9216                         // mean 8163 + ~11 sigma
#define CURPAD 16                           // global counters padded to 64B
#define PH     2048                         // edges per partition phase

typedef __attribute__((ext_vector_type(8))) short short8v;  // 8 x bf16
typedef __attribute__((ext_vector_type(4))) float f32x4;

static __device__ __forceinline__ unsigned short f2bf(float v) {
    __hip_bfloat16 b = __float2bfloat16(v);
    return *reinterpret_cast<unsigned short*>(&b);
}
static __device__ __forceinline__ float bfhi2f(unsigned int u) {
    union { unsigned int i; float f; } x; x.i = u & 0xFFFF0000u; return x.f;
}
static __device__ __forceinline__ float bflo2f(unsigned int u) {
    union { unsigned int i; float f; } x; x.i = u << 16; return x.f;
}

// ---------------- Both W transposes to bf16 in one kernel ----------------
__global__ __launch_bounds__(256) void wtrans2_kernel(const float* __restrict__ W1,
                                                      const float* __restrict__ W2,
                                                      unsigned short* __restrict__ Wt1,
                                                      unsigned short* __restrict__ Wt2) {
    int i = blockIdx.x * 256 + threadIdx.x;
    if (i < DIN * NHID) {
        const int k = i >> 7, c = i & 127;
        Wt1[c * DIN + k] = f2bf(W1[i]);
    } else {
        i -= DIN * NHID;
        if (i < NHID * NHID) {
            const int k = i >> 7, c = i & 127;
            Wt2[c * NHID + k] = f2bf(W2[i]);
        }
    }
}

// ---------------- MFMA GEMM: C[M][128] = A[M][K] @ W[K][128], no big LDS ----------------
// B-fragments load directly from global pre-transposed bf16 Wtb (L1/L2-resident).
// MODE 0: A fp32 -> bf16 (layer 1). MODE 1: fused BN(scale/shift)+ReLU (layer 2).
template <int K, int MODE>
__global__ __launch_bounds__(256) void mfma_gemm(const float* __restrict__ Af,
                                                 const unsigned short* __restrict__ Wtb,
                                                 const float* __restrict__ SS,
                                                 unsigned short* __restrict__ C, int M) {
    __shared__ float ssl[256];
    const int t = threadIdx.x;
    if (MODE == 1) {
        if (t < 256) ssl[t] = SS[t];
        __syncthreads();
    }

    const int wid = t >> 6;
    const int lane = t & 63;
    const int wr = wid >> 1, wc = wid & 1;
    const int l15 = lane & 15, g = lane >> 4;
    const int R0 = blockIdx.x * 128 + wr * 64;

    f32x4 acc[4][4] = {};

    for (int s = 0; s < K / 32; ++s) {
        short8v b[4];
#pragma unroll
        for (int n = 0; n < 4; ++n) {
            const int col = wc * 64 + n * 16 + l15;
            b[n] = *reinterpret_cast<const short8v*>(&Wtb[(size_t)col * K + s * 32 + g * 8]);
        }
        float sc[8], sh[8];
        if (MODE == 1) {
#pragma unroll
            for (int j = 0; j < 8; ++j) {
                sc[j] = ssl[s * 32 + g * 8 + j];
                sh[j] = ssl[128 + s * 32 + g * 8 + j];
            }
        }
        short8v a[4];
#pragma unroll
        for (int m = 0; m < 4; ++m) {
            int row = R0 + m * 16 + l15;
            row = row < M ? row : M - 1;   // clamp; pad rows discarded at store
            const float* p = Af + (size_t)row * K + s * 32 + g * 8;
            const float4 v0 = *reinterpret_cast<const float4*>(p);
            const float4 v1 = *reinterpret_cast<const float4*>(p + 4);
            float vv[8] = {v0.x, v0.y, v0.z, v0.w, v1.x, v1.y, v1.z, v1.w};
            short8v av;
#pragma unroll
            for (int j = 0; j < 8; ++j) {
                float y = vv[j];
                if (MODE == 1) y = fmaxf(fmaf(y, sc[j], sh[j]), 0.f);
                av[j] = (short)f2bf(y);
            }
            a[m] = av;
        }
#pragma unroll
        for (int m = 0; m < 4; ++m)
#pragma unroll
            for (int n = 0; n < 4; ++n)
                acc[m][n] = __builtin_amdgcn_mfma_f32_16x16x32_bf16(a[m], b[n], acc[m][n], 0, 0, 0);
    }

    // C/D layout: col = lane&15, row = (lane>>4)*4 + q
#pragma unroll
    for (int m = 0; m < 4; ++m) {
#pragma unroll
        for (int q = 0; q < 4; ++q) {
            const int row = R0 + m * 16 + g * 4 + q;
            if (row < M) {
                unsigned short* cp = C + (size_t)row * NHID + wc * 64 + l15;
#pragma unroll
                for (int n = 0; n < 4; ++n)
                    cp[n * 16] = f2bf(acc[m][n][q]);
            }
        }
    }
}

// ---------------- Pass A: phase-sorted partition into 196 buckets ----------------
__global__ __launch_bounds__(256) void part_kernel(const int* __restrict__ src,
                                                   const int* __restrict__ dst,
                                                   const float* __restrict__ w,
                                                   int* __restrict__ gcur,
                                                   int2* __restrict__ bstage, int E) {
    __shared__ int2 staged[PH];
    __shared__ unsigned char aux[PH];
    __shared__ int hist[NB2], scn[NB2], cur[NB2], gbase[NB2];
    __shared__ int part[256];

    const int t = threadIdx.x;
    const int nchunk = (E + PH - 1) / PH;
    for (int c = blockIdx.x; c < nchunk; c += gridDim.x) {
        const int e0 = c * PH;
        const int cnt = min(PH, E - e0);
        for (int i = t; i < NB2; i += 256) hist[i] = 0;
        __syncthreads();

        int2 pay[8];
        int bk[8];
#pragma unroll
        for (int j = 0; j < 8; ++j) {
            const int i = j * 256 + t;
            bk[j] = -1;
            if (i < cnt) {
                const int e = e0 + i;
                const int d = dst[e];
                bk[j] = d >> SHIFT;
                pay[j].x = src[e] | ((d & 511) << 17);   // src < 2^17, dst low9 in [17..25]
                pay[j].y = __float_as_int(w[e]);
                atomicAdd(&hist[bk[j]], 1);
            }
        }
        __syncthreads();

        // exclusive scan over NB2 bins
        part[t] = (t < NB2) ? hist[t] : 0;
        __syncthreads();
        for (int off = 1; off < 256; off <<= 1) {
            const int v = (t >= off) ? part[t - off] : 0;
            __syncthreads();
            part[t] += v;
            __syncthreads();
        }
        if (t < NB2) {
            const int ex = part[t] - hist[t];
            scn[t] = ex;
            cur[t] = ex;
        }
        __syncthreads();

        // scatter into bucket-grouped LDS staging
#pragma unroll
        for (int j = 0; j < 8; ++j) {
            if (bk[j] >= 0) {
                const int p = atomicAdd(&cur[bk[j]], 1);
                staged[p] = pay[j];
                aux[p] = (unsigned char)bk[j];
            }
        }
        // claim global space (one atomic per non-empty bucket)
        if (t < NB2 && hist[t] > 0) gbase[t] = atomicAdd(&gcur[t * CURPAD], hist[t]);
        __syncthreads();

        // coalesced run writes
        for (int i = t; i < cnt; i += 256) {
            const int b = aux[i];
            const int p = gbase[b] + (i - scn[b]);
            if (p < BCAP2) bstage[(size_t)b * BCAP2 + p] = staged[i];
        }
        __syncthreads();
    }
}

// ---------------- Pass B: per-bucket exact CSR (512 bins, 196 blocks) ----------------
__global__ __launch_bounds__(256) void csr_kernel(const int* __restrict__ gcur,
                                                  const int2* __restrict__ bstage,
                                                  int2* __restrict__ row_be,
                                                  int2* __restrict__ s_iw) {
    const int b = blockIdx.x;
    const int t = threadIdx.x;
    int cnt = gcur[b * CURPAD];
    if (cnt > BCAP2) cnt = BCAP2;
    const int sbase = b * BCAP2;

    __shared__ int hist[512], cur[512];
    __shared__ int part[256];
    for (int i = t; i < 512; i += 256) hist[i] = 0;
    __syncthreads();
    for (int i = t; i < cnt; i += 256)
        atomicAdd(&hist[(bstage[sbase + i].x >> 17) & 511], 1);
    __syncthreads();

    // scan 512 bins: thread t owns bins 2t, 2t+1
    int loc[2];
    loc[0] = hist[t * 2];
    loc[1] = hist[t * 2 + 1];
    const int s0 = loc[0] + loc[1];
    part[t] = s0;
    __syncthreads();
    for (int off = 1; off < 256; off <<= 1) {
        const int v = (t >= off) ? part[t - off] : 0;
        __syncthreads();
        part[t] += v;
        __syncthreads();
    }
    int run = part[t] - s0;
#pragma unroll
    for (int j = 0; j < 2; ++j) {
        const int lb = t * 2 + j;
        cur[lb] = run;
        const int d = (b << SHIFT) + lb;
        if (d < NNODES) {
            int2 be;
            be.x = sbase + run;
            be.y = sbase + run + loc[j];
            row_be[d] = be;
        }
        run += loc[j];
    }
    __syncthreads();

    for (int i = t; i < cnt; i += 256) {
        const int2 e = bstage[sbase + i];
        const int l = (e.x >> 17) & 511;
        const int p = atomicAdd(&cur[l], 1);
        int2 o;
        o.x = e.x & 0x1FFFF;
        o.y = e.y;
        s_iw[sbase + p] = o;
    }
}

// ---------------- Aggregate: 16-lane edge groups, uint4 loads, 4 edges/wave in flight ----------------
__global__ __launch_bounds__(256) void aggregate_kernel(const unsigned short* __restrict__ hb,
                                                        const int2* __restrict__ row_be,
                                                        const int2* __restrict__ s_iw,
                                                        float* __restrict__ out, int n) {
    const int wid = (blockIdx.x * 256 + threadIdx.x) >> 6;
    if (wid >= n) return;
    const int lane = threadIdx.x & 63;
    const int grp = lane >> 4;     // edge slot 0..3
    const int l16 = lane & 15;     // col group: cols l16*8 .. +7
    const int2 be = row_be[wid];
    const int end = be.y;

    float acc[8] = {};
    int j = be.x + grp;
    for (; j + 4 < end; j += 8) {
        const int2 e0 = s_iw[j];
        const int2 e1 = s_iw[j + 4];
        const uint4 v0 = *reinterpret_cast<const uint4*>(hb + (size_t)e0.x * NHID + l16 * 8);
        const uint4 v1 = *reinterpret_cast<const uint4*>(hb + (size_t)e1.x * NHID + l16 * 8);
        const float w0 = __int_as_float(e0.y);
        const float w1 = __int_as_float(e1.y);
        acc[0] = fmaf(w0, bflo2f(v0.x), acc[0]); acc[1] = fmaf(w0, bfhi2f(v0.x), acc[1]);
        acc[2] = fmaf(w0, bflo2f(v0.y), acc[2]); acc[3] = fmaf(w0, bfhi2f(v0.y), acc[3]);
        acc[4] = fmaf(w0, bflo2f(v0.z), acc[4]); acc[5] = fmaf(w0, bfhi2f(v0.z), acc[5]);
        acc[6] = fmaf(w0, bflo2f(v0.w), acc[6]); acc[7] = fmaf(w0, bfhi2f(v0.w), acc[7]);
        acc[0] = fmaf(w1, bflo2f(v1.x), acc[0]); acc[1] = fmaf(w1, bfhi2f(v1.x), acc[1]);
        acc[2] = fmaf(w1, bflo2f(v1.y), acc[2]); acc[3] = fmaf(w1, bfhi2f(v1.y), acc[3]);
        acc[4] = fmaf(w1, bflo2f(v1.z), acc[4]); acc[5] = fmaf(w1, bfhi2f(v1.z), acc[5]);
        acc[6] = fmaf(w1, bflo2f(v1.w), acc[6]); acc[7] = fmaf(w1, bfhi2f(v1.w), acc[7]);
    }
    if (j < end) {
        const int2 e0 = s_iw[j];
        const uint4 v0 = *reinterpret_cast<const uint4*>(hb + (size_t)e0.x * NHID + l16 * 8);
        const float w0 = __int_as_float(e0.y);
        acc[0] = fmaf(w0, bflo2f(v0.x), acc[0]); acc[1] = fmaf(w0, bfhi2f(v0.x), acc[1]);
        acc[2] = fmaf(w0, bflo2f(v0.y), acc[2]); acc[3] = fmaf(w0, bfhi2f(v0.y), acc[3]);
        acc[4] = fmaf(w0, bflo2f(v0.z), acc[4]); acc[5] = fmaf(w0, bfhi2f(v0.z), acc[5]);
        acc[6] = fmaf(w0, bflo2f(v0.w), acc[6]); acc[7] = fmaf(w0, bfhi2f(v0.w), acc[7]);
    }
    // combine the 4 edge groups
#pragma unroll
    for (int k = 0; k < 8; ++k) {
        acc[k] += __shfl_xor(acc[k], 16, 64);
        acc[k] += __shfl_xor(acc[k], 32, 64);
    }
    if (grp == 0) {
        float4 a, b;
        a.x = acc[0]; a.y = acc[1]; a.z = acc[2]; a.w = acc[3];
        b.x = acc[4]; b.y = acc[5]; b.z = acc[6]; b.w = acc[7];
        float4* op = reinterpret_cast<float4*>(out + (size_t)wid * NHID + l16 * 8);
        op[0] = a;
        op[1] = b;
    }
}

// ---------------- BN stats / finalize / final apply ----------------
__global__ __launch_bounds__(256) void stats_kernel(const float* __restrict__ h,
                                                    float* __restrict__ sums, int nrows) {
    const int col = threadIdx.x & 127;
    const int half = threadIdx.x >> 7;
    float s = 0.f, sq = 0.f;
    for (int r = blockIdx.x * 2 + half; r < nrows; r += gridDim.x * 2) {
        const float v = h[(size_t)r * NHID + col];
        s += v;
        sq += v * v;
    }
    __shared__ float ls[256], lq[256];
    ls[threadIdx.x] = s;
    lq[threadIdx.x] = sq;
    __syncthreads();
    if (threadIdx.x < 128) {
        atomicAdd(&sums[col], ls[threadIdx.x] + ls[threadIdx.x + 128]);
        atomicAdd(&sums[128 + col], lq[threadIdx.x] + lq[threadIdx.x + 128]);
    }
}

__global__ void finalize_kernel(const float* __restrict__ sums,
                                const float* __restrict__ gamma,
                                const float* __restrict__ beta,
                                float* __restrict__ ss) {
    const int c = threadIdx.x;
    const float invN = 1.0f / (float)NNODES;
    const float mean = sums[c] * invN;
    const float var = sums[128 + c] * invN - mean * mean;
    const float scale = gamma[c] * rsqrtf(var + EPS);
    ss[c] = scale;
    ss[128 + c] = beta[c] - mean * scale;
}

__global__ __launch_bounds__(256) void apply_f32_kernel(const float* __restrict__ in,
                                                        const float* __restrict__ ss,
                                                        float* __restrict__ out, int n4) {
    const int idx = blockIdx.x * 256 + threadIdx.x;
    if (idx >= n4) return;
    const int c = (idx & 31) * 4;
    const float4 v = reinterpret_cast<const float4*>(in)[idx];
    const float4 sc = *reinterpret_cast<const float4*>(ss + c);
    const float4 sh = *reinterpret_cast<const float4*>(ss + 128 + c);
    float4 r;
    r.x = fmaxf(fmaf(v.x, sc.x, sh.x), 0.f);
    r.y = fmaxf(fmaf(v.y, sc.y, sh.y), 0.f);
    r.z = fmaxf(fmaf(v.z, sc.z, sh.z), 0.f);
    r.w = fmaxf(fmaf(v.w, sc.w, sh.w), 0.f);
    reinterpret_cast<float4*>(out)[idx] = r;
}

extern "C" void kernel_launch(void* const* d_in, const int* in_sizes, int n_in,
                              void* d_out, int out_size, void* d_ws, size_t ws_size,
                              hipStream_t stream) {
    const float* x   = (const float*)d_in[0];
    const int*   ei  = (const int*)d_in[1];
    const float* ew  = (const float*)d_in[2];
    const float* W1  = (const float*)d_in[3];
    const float* g1  = (const float*)d_in[5];
    const float* be1 = (const float*)d_in[6];
    const float* W2  = (const float*)d_in[7];
    const float* g2  = (const float*)d_in[9];
    const float* be2 = (const float*)d_in[10];
    float* out = (float*)d_out;

    const int M = NNODES;
    const int E = in_sizes[2];
    const int* src = ei;
    const int* dst = ei + E;

    // workspace layout (~107 MB)
    unsigned short* hb = (unsigned short*)d_ws;               // M*128 bf16 (25.6 MB)
    float* agg   = (float*)(hb + (size_t)M * NHID);           // M*128 fp32 (51.2 MB)
    int2* bstage = (int2*)(agg + (size_t)M * NHID);           // NB2*BCAP2 (14.5 MB)
    int2* s_iw   = bstage + (size_t)NB2 * BCAP2;              // NB2*BCAP2 (14.5 MB)
    int2* row_be = s_iw + (size_t)NB2 * BCAP2;                // N (800 KB)
    int* gcur    = (int*)(row_be + NNODES);                   // NB2*CURPAD (12.5 KB)
    unsigned short* Wt1b = (unsigned short*)(gcur + NB2 * CURPAD);  // 256*128 bf16
    unsigned short* Wt2b = Wt1b + DIN * NHID;                 // 128*128 bf16
    float* sums  = (float*)(Wt2b + NHID * NHID);              // 512 (both layers)
    float* ss    = sums + 512;                                // 256

    const int gemm_grid = (M + 127) / 128;
    const int n4 = M * NHID / 4;
    const int app_grid = (n4 + 255) / 256;
    const int agg_grid = (M * 64 + 255) / 256;
    const int part_grid = (E + PH - 1) / PH;

    // ---- Prep: W transposes + CSR build + stats zero ----
    wtrans2_kernel<<<(DIN * NHID + NHID * NHID + 255) / 256, 256, 0, stream>>>(W1, W2, Wt1b, Wt2b);
    hipMemsetAsync(gcur, 0, (size_t)NB2 * CURPAD * sizeof(int), stream);
    hipMemsetAsync(sums, 0, 512 * sizeof(float), stream);
    part_kernel<<<part_grid, 256, 0, stream>>>(src, dst, ew, gcur, bstage, E);
    csr_kernel<<<NB2, 256, 0, stream>>>(gcur, bstage, row_be, s_iw);

    // ---- Layer 1 ----
    mfma_gemm<DIN, 0><<<gemm_grid, 256, 0, stream>>>(x, Wt1b, nullptr, hb, M);
    aggregate_kernel<<<agg_grid, 256, 0, stream>>>(hb, row_be, s_iw, agg, M);
    stats_kernel<<<1024, 256, 0, stream>>>(agg, sums, M);
    finalize_kernel<<<1, 128, 0, stream>>>(sums, g1, be1, ss);

    // ---- Layer 2 (BN1+ReLU fused into GEMM2's A-load) ----
    mfma_gemm<NHID, 1><<<gemm_grid, 256, 0, stream>>>(agg, Wt2b, ss, hb, M);
    aggregate_kernel<<<agg_grid, 256, 0, stream>>>(hb, row_be, s_iw, agg, M);
    stats_kernel<<<1024, 256, 0, stream>>>(agg, sums + 256, M);
    finalize_kernel<<<1, 128, 0, stream>>>(sums + 256, g2, be2, ss);
    apply_f32_kernel<<<app_grid, 256, 0, stream>>>(agg, ss, out, n4);
}

// Round 10
// 344.745 us; speedup vs baseline: 1.2918x; 1.0529x over previous
//
#include <hip/hip_runtime.h>
#include <hip/hip_bf16.h>

#define NNODES 100000
#define DIN    256
#define NHID   128
#define EPS    1e-5f
#define SHIFT  9
#define NB2    ((NNODES + 511) >> SHIFT)    // 196 buckets of 512 dst
#define BCAP2  9216                         // mean 8163 + ~11 sigma
#define CURPAD 16                           // global counters padded to 64B
#define PH     2048                         // edges per partition phase

typedef __attribute__((ext_vector_type(8))) short short8v;  // 8 x bf16
typedef __attribute__((ext_vector_type(4))) float f32x4;

static __device__ __forceinline__ unsigned short f2bf(float v) {
    __hip_bfloat16 b = __float2bfloat16(v);
    return *reinterpret_cast<unsigned short*>(&b);
}
static __device__ __forceinline__ float bfhi2f(unsigned int u) {
    union { unsigned int i; float f; } x; x.i = u & 0xFFFF0000u; return x.f;
}
static __device__ __forceinline__ float bflo2f(unsigned int u) {
    union { unsigned int i; float f; } x; x.i = u << 16; return x.f;
}

// ---------------- Both W transposes to bf16 in one kernel ----------------
__global__ __launch_bounds__(256) void wtrans2_kernel(const float* __restrict__ W1,
                                                      const float* __restrict__ W2,
                                                      unsigned short* __restrict__ Wt1,
                                                      unsigned short* __restrict__ Wt2) {
    int i = blockIdx.x * 256 + threadIdx.x;
    if (i < DIN * NHID) {
        const int k = i >> 7, c = i & 127;
        Wt1[c * DIN + k] = f2bf(W1[i]);
    } else {
        i -= DIN * NHID;
        if (i < NHID * NHID) {
            const int k = i >> 7, c = i & 127;
            Wt2[c * NHID + k] = f2bf(W2[i]);
        }
    }
}

// ---------------- MFMA GEMM with LDS-staged, double-buffered A ----------------
// A is staged 128x32 per slice, bf16-converted at staging (coalesced global reads,
// each line fetched once per block). B-fragments direct from L1/L2-resident Wtb.
// MODE 0: plain convert (layer 1). MODE 1: fused BN(scale/shift)+ReLU at staging (layer 2).
template <int K, int MODE>
__global__ __launch_bounds__(256) void mfma_gemm(const float* __restrict__ Af,
                                                 const unsigned short* __restrict__ Wtb,
                                                 const float* __restrict__ SS,
                                                 unsigned short* __restrict__ C, int M) {
    constexpr int NS = K / 32;
    constexpr int PADB = 40;                       // bf16 row stride in LDS
    __shared__ unsigned short As[2][128 * PADB];   // 2 x 10 KB
    __shared__ float ssl[256];

    const int t = threadIdx.x;
    if (MODE == 1) {
        ssl[t] = SS[t];
        __syncthreads();
    }

    const int wid = t >> 6;
    const int lane = t & 63;
    const int wr = wid >> 1, wc = wid & 1;
    const int l15 = lane & 15, g = lane >> 4;
    const int R0 = blockIdx.x * 128;
    const int RW = R0 + wr * 64;

    const int srow = t >> 3;        // staging row 0..31 (+i*32)
    const int scol = (t & 7) * 4;   // staging col group (fp32 cols)

    f32x4 acc[4][4] = {};

    auto STAGE = [&](int s, int buf) {
        const int k0 = s * 32;
#pragma unroll
        for (int i = 0; i < 4; ++i) {
            const int row = srow + i * 32;
            int grow = R0 + row;
            grow = grow < M ? grow : M - 1;   // clamp; pad rows discarded at store
            float4 v = *reinterpret_cast<const float4*>(Af + (size_t)grow * K + k0 + scol);
            if (MODE == 1) {
                v.x = fmaxf(fmaf(v.x, ssl[k0 + scol],     ssl[128 + k0 + scol]),     0.f);
                v.y = fmaxf(fmaf(v.y, ssl[k0 + scol + 1], ssl[128 + k0 + scol + 1]), 0.f);
                v.z = fmaxf(fmaf(v.z, ssl[k0 + scol + 2], ssl[128 + k0 + scol + 2]), 0.f);
                v.w = fmaxf(fmaf(v.w, ssl[k0 + scol + 3], ssl[128 + k0 + scol + 3]), 0.f);
            }
            ushort4 bv;
            bv.x = f2bf(v.x); bv.y = f2bf(v.y); bv.z = f2bf(v.z); bv.w = f2bf(v.w);
            *reinterpret_cast<ushort4*>(&As[buf][row * PADB + scol]) = bv;
        }
    };

    STAGE(0, 0);
    __syncthreads();

    for (int s = 0; s < NS; ++s) {
        if (s + 1 < NS) STAGE(s + 1, (s + 1) & 1);   // prefetch next slice into other buffer
        const unsigned short* ab = As[s & 1];
        short8v b[4];
#pragma unroll
        for (int n = 0; n < 4; ++n) {
            const int col = wc * 64 + n * 16 + l15;
            b[n] = *reinterpret_cast<const short8v*>(&Wtb[(size_t)col * K + s * 32 + g * 8]);
        }
        short8v a[4];
#pragma unroll
        for (int m = 0; m < 4; ++m) {
            const int row = wr * 64 + m * 16 + l15;
            a[m] = *reinterpret_cast<const short8v*>(&ab[row * PADB + g * 8]);
        }
#pragma unroll
        for (int m = 0; m < 4; ++m)
#pragma unroll
            for (int n = 0; n < 4; ++n)
                acc[m][n] = __builtin_amdgcn_mfma_f32_16x16x32_bf16(a[m], b[n], acc[m][n], 0, 0, 0);
        __syncthreads();
    }

    // C/D layout: col = lane&15, row = (lane>>4)*4 + q
#pragma unroll
    for (int m = 0; m < 4; ++m) {
#pragma unroll
        for (int q = 0; q < 4; ++q) {
            const int row = RW + m * 16 + g * 4 + q;
            if (row < M) {
                unsigned short* cp = C + (size_t)row * NHID + wc * 64 + l15;
#pragma unroll
                for (int n = 0; n < 4; ++n)
                    cp[n * 16] = f2bf(acc[m][n][q]);
            }
        }
    }
}

// ---------------- Pass A: phase-sorted partition into 196 buckets ----------------
__global__ __launch_bounds__(256) void part_kernel(const int* __restrict__ src,
                                                   const int* __restrict__ dst,
                                                   const float* __restrict__ w,
                                                   int* __restrict__ gcur,
                                                   int2* __restrict__ bstage, int E) {
    __shared__ int2 staged[PH];
    __shared__ unsigned char aux[PH];
    __shared__ int hist[NB2], scn[NB2], cur[NB2], gbase[NB2];
    __shared__ int part[256];

    const int t = threadIdx.x;
    const int nchunk = (E + PH - 1) / PH;
    for (int c = blockIdx.x; c < nchunk; c += gridDim.x) {
        const int e0 = c * PH;
        const int cnt = min(PH, E - e0);
        for (int i = t; i < NB2; i += 256) hist[i] = 0;
        __syncthreads();

        int2 pay[8];
        int bk[8];
#pragma unroll
        for (int j = 0; j < 8; ++j) {
            const int i = j * 256 + t;
            bk[j] = -1;
            if (i < cnt) {
                const int e = e0 + i;
                const int d = dst[e];
                bk[j] = d >> SHIFT;
                pay[j].x = src[e] | ((d & 511) << 17);   // src < 2^17, dst low9 in [17..25]
                pay[j].y = __float_as_int(w[e]);
                atomicAdd(&hist[bk[j]], 1);
            }
        }
        __syncthreads();

        // exclusive scan over NB2 bins
        part[t] = (t < NB2) ? hist[t] : 0;
        __syncthreads();
        for (int off = 1; off < 256; off <<= 1) {
            const int v = (t >= off) ? part[t - off] : 0;
            __syncthreads();
            part[t] += v;
            __syncthreads();
        }
        if (t < NB2) {
            const int ex = part[t] - hist[t];
            scn[t] = ex;
            cur[t] = ex;
        }
        __syncthreads();

        // scatter into bucket-grouped LDS staging
#pragma unroll
        for (int j = 0; j < 8; ++j) {
            if (bk[j] >= 0) {
                const int p = atomicAdd(&cur[bk[j]], 1);
                staged[p] = pay[j];
                aux[p] = (unsigned char)bk[j];
            }
        }
        // claim global space (one atomic per non-empty bucket)
        if (t < NB2 && hist[t] > 0) gbase[t] = atomicAdd(&gcur[t * CURPAD], hist[t]);
        __syncthreads();

        // coalesced run writes
        for (int i = t; i < cnt; i += 256) {
            const int b = aux[i];
            const int p = gbase[b] + (i - scn[b]);
            if (p < BCAP2) bstage[(size_t)b * BCAP2 + p] = staged[i];
        }
        __syncthreads();
    }
}

// ---------------- Pass B: per-bucket exact CSR (512 bins, 196 blocks) ----------------
__global__ __launch_bounds__(256) void csr_kernel(const int* __restrict__ gcur,
                                                  const int2* __restrict__ bstage,
                                                  int2* __restrict__ row_be,
                                                  int2* __restrict__ s_iw) {
    const int b = blockIdx.x;
    const int t = threadIdx.x;
    int cnt = gcur[b * CURPAD];
    if (cnt > BCAP2) cnt = BCAP2;
    const int sbase = b * BCAP2;

    __shared__ int hist[512], cur[512];
    __shared__ int part[256];
    for (int i = t; i < 512; i += 256) hist[i] = 0;
    __syncthreads();
    for (int i = t; i < cnt; i += 256)
        atomicAdd(&hist[(bstage[sbase + i].x >> 17) & 511], 1);
    __syncthreads();

    // scan 512 bins: thread t owns bins 2t, 2t+1
    int loc[2];
    loc[0] = hist[t * 2];
    loc[1] = hist[t * 2 + 1];
    const int s0 = loc[0] + loc[1];
    part[t] = s0;
    __syncthreads();
    for (int off = 1; off < 256; off <<= 1) {
        const int v = (t >= off) ? part[t - off] : 0;
        __syncthreads();
        part[t] += v;
        __syncthreads();
    }
    int run = part[t] - s0;
#pragma unroll
    for (int j = 0; j < 2; ++j) {
        const int lb = t * 2 + j;
        cur[lb] = run;
        const int d = (b << SHIFT) + lb;
        if (d < NNODES) {
            int2 be;
            be.x = sbase + run;
            be.y = sbase + run + loc[j];
            row_be[d] = be;
        }
        run += loc[j];
    }
    __syncthreads();

    for (int i = t; i < cnt; i += 256) {
        const int2 e = bstage[sbase + i];
        const int l = (e.x >> 17) & 511;
        const int p = atomicAdd(&cur[l], 1);
        int2 o;
        o.x = e.x & 0x1FFFF;
        o.y = e.y;
        s_iw[sbase + p] = o;
    }
}

// ---------------- Aggregate: 16-lane edge groups, uint4 loads, 4 edges/wave in flight ----------------
__global__ __launch_bounds__(256) void aggregate_kernel(const unsigned short* __restrict__ hb,
                                                        const int2* __restrict__ row_be,
                                                        const int2* __restrict__ s_iw,
                                                        float* __restrict__ out, int n) {
    const int wid = (blockIdx.x * 256 + threadIdx.x) >> 6;
    if (wid >= n) return;
    const int lane = threadIdx.x & 63;
    const int grp = lane >> 4;     // edge slot 0..3
    const int l16 = lane & 15;     // col group: cols l16*8 .. +7
    const int2 be = row_be[wid];
    const int end = be.y;

    float acc[8] = {};
    int j = be.x + grp;
    for (; j + 4 < end; j += 8) {
        const int2 e0 = s_iw[j];
        const int2 e1 = s_iw[j + 4];
        const uint4 v0 = *reinterpret_cast<const uint4*>(hb + (size_t)e0.x * NHID + l16 * 8);
        const uint4 v1 = *reinterpret_cast<const uint4*>(hb + (size_t)e1.x * NHID + l16 * 8);
        const float w0 = __int_as_float(e0.y);
        const float w1 = __int_as_float(e1.y);
        acc[0] = fmaf(w0, bflo2f(v0.x), acc[0]); acc[1] = fmaf(w0, bfhi2f(v0.x), acc[1]);
        acc[2] = fmaf(w0, bflo2f(v0.y), acc[2]); acc[3] = fmaf(w0, bfhi2f(v0.y), acc[3]);
        acc[4] = fmaf(w0, bflo2f(v0.z), acc[4]); acc[5] = fmaf(w0, bfhi2f(v0.z), acc[5]);
        acc[6] = fmaf(w0, bflo2f(v0.w), acc[6]); acc[7] = fmaf(w0, bfhi2f(v0.w), acc[7]);
        acc[0] = fmaf(w1, bflo2f(v1.x), acc[0]); acc[1] = fmaf(w1, bfhi2f(v1.x), acc[1]);
        acc[2] = fmaf(w1, bflo2f(v1.y), acc[2]); acc[3] = fmaf(w1, bfhi2f(v1.y), acc[3]);
        acc[4] = fmaf(w1, bflo2f(v1.z), acc[4]); acc[5] = fmaf(w1, bfhi2f(v1.z), acc[5]);
        acc[6] = fmaf(w1, bflo2f(v1.w), acc[6]); acc[7] = fmaf(w1, bfhi2f(v1.w), acc[7]);
    }
    if (j < end) {
        const int2 e0 = s_iw[j];
        const uint4 v0 = *reinterpret_cast<const uint4*>(hb + (size_t)e0.x * NHID + l16 * 8);
        const float w0 = __int_as_float(e0.y);
        acc[0] = fmaf(w0, bflo2f(v0.x), acc[0]); acc[1] = fmaf(w0, bfhi2f(v0.x), acc[1]);
        acc[2] = fmaf(w0, bflo2f(v0.y), acc[2]); acc[3] = fmaf(w0, bfhi2f(v0.y), acc[3]);
        acc[4] = fmaf(w0, bflo2f(v0.z), acc[4]); acc[5] = fmaf(w0, bfhi2f(v0.z), acc[5]);
        acc[6] = fmaf(w0, bflo2f(v0.w), acc[6]); acc[7] = fmaf(w0, bfhi2f(v0.w), acc[7]);
    }
    // combine the 4 edge groups
#pragma unroll
    for (int k = 0; k < 8; ++k) {
        acc[k] += __shfl_xor(acc[k], 16, 64);
        acc[k] += __shfl_xor(acc[k], 32, 64);
    }
    if (grp == 0) {
        float4 a, b;
        a.x = acc[0]; a.y = acc[1]; a.z = acc[2]; a.w = acc[3];
        b.x = acc[4]; b.y = acc[5]; b.z = acc[6]; b.w = acc[7];
        float4* op = reinterpret_cast<float4*>(out + (size_t)wid * NHID + l16 * 8);
        op[0] = a;
        op[1] = b;
    }
}

// ---------------- BN stats / finalize / final apply ----------------
__global__ __launch_bounds__(256) void stats_kernel(const float* __restrict__ h,
                                                    float* __restrict__ sums, int nrows) {
    const int col = threadIdx.x & 127;
    const int half = threadIdx.x >> 7;
    float s = 0.f, sq = 0.f;
    for (int r = blockIdx.x * 2 + half; r < nrows; r += gridDim.x * 2) {
        const float v = h[(size_t)r * NHID + col];
        s += v;
        sq += v * v;
    }
    __shared__ float ls[256], lq[256];
    ls[threadIdx.x] = s;
    lq[threadIdx.x] = sq;
    __syncthreads();
    if (threadIdx.x < 128) {
        atomicAdd(&sums[col], ls[threadIdx.x] + ls[threadIdx.x + 128]);
        atomicAdd(&sums[128 + col], lq[threadIdx.x] + lq[threadIdx.x + 128]);
    }
}

__global__ void finalize_kernel(const float* __restrict__ sums,
                                const float* __restrict__ gamma,
                                const float* __restrict__ beta,
                                float* __restrict__ ss) {
    const int c = threadIdx.x;
    const float invN = 1.0f / (float)NNODES;
    const float mean = sums[c] * invN;
    const float var = sums[128 + c] * invN - mean * mean;
    const float scale = gamma[c] * rsqrtf(var + EPS);
    ss[c] = scale;
    ss[128 + c] = beta[c] - mean * scale;
}

__global__ __launch_bounds__(256) void apply_f32_kernel(const float* __restrict__ in,
                                                        const float* __restrict__ ss,
                                                        float* __restrict__ out, int n4) {
    const int idx = blockIdx.x * 256 + threadIdx.x;
    if (idx >= n4) return;
    const int c = (idx & 31) * 4;
    const float4 v = reinterpret_cast<const float4*>(in)[idx];
    const float4 sc = *reinterpret_cast<const float4*>(ss + c);
    const float4 sh = *reinterpret_cast<const float4*>(ss + 128 + c);
    float4 r;
    r.x = fmaxf(fmaf(v.x, sc.x, sh.x), 0.f);
    r.y = fmaxf(fmaf(v.y, sc.y, sh.y), 0.f);
    r.z = fmaxf(fmaf(v.z, sc.z, sh.z), 0.f);
    r.w = fmaxf(fmaf(v.w, sc.w, sh.w), 0.f);
    reinterpret_cast<float4*>(out)[idx] = r;
}

extern "C" void kernel_launch(void* const* d_in, const int* in_sizes, int n_in,
                              void* d_out, int out_size, void* d_ws, size_t ws_size,
                              hipStream_t stream) {
    const float* x   = (const float*)d_in[0];
    const int*   ei  = (const int*)d_in[1];
    const float* ew  = (const float*)d_in[2];
    const float* W1  = (const float*)d_in[3];
    const float* g1  = (const float*)d_in[5];
    const float* be1 = (const float*)d_in[6];
    const float* W2  = (const float*)d_in[7];
    const float* g2  = (const float*)d_in[9];
    const float* be2 = (const float*)d_in[10];
    float* out = (float*)d_out;

    const int M = NNODES;
    const int E = in_sizes[2];
    const int* src = ei;
    const int* dst = ei + E;

    // workspace layout (~107 MB)
    unsigned short* hb = (unsigned short*)d_ws;               // M*128 bf16 (25.6 MB)
    float* agg   = (float*)(hb + (size_t)M * NHID);           // M*128 fp32 (51.2 MB)
    int2* bstage = (int2*)(agg + (size_t)M * NHID);           // NB2*BCAP2 (14.5 MB)
    int2* s_iw   = bstage + (size_t)NB2 * BCAP2;              // NB2*BCAP2 (14.5 MB)
    int2* row_be = s_iw + (size_t)NB2 * BCAP2;                // N (800 KB)
    int* gcur    = (int*)(row_be + NNODES);                   // NB2*CURPAD (12.5 KB)
    unsigned short* Wt1b = (unsigned short*)(gcur + NB2 * CURPAD);  // 256*128 bf16
    unsigned short* Wt2b = Wt1b + DIN * NHID;                 // 128*128 bf16
    float* sums  = (float*)(Wt2b + NHID * NHID);              // 512 (both layers)
    float* ss    = sums + 512;                                // 256

    const int gemm_grid = (M + 127) / 128;
    const int n4 = M * NHID / 4;
    const int app_grid = (n4 + 255) / 256;
    const int agg_grid = (M * 64 + 255) / 256;
    const int part_grid = (E + PH - 1) / PH;

    // ---- Prep: W transposes + CSR build + stats zero ----
    wtrans2_kernel<<<(DIN * NHID + NHID * NHID + 255) / 256, 256, 0, stream>>>(W1, W2, Wt1b, Wt2b);
    hipMemsetAsync(gcur, 0, (size_t)NB2 * CURPAD * sizeof(int), stream);
    hipMemsetAsync(sums, 0, 512 * sizeof(float), stream);
    part_kernel<<<part_grid, 256, 0, stream>>>(src, dst, ew, gcur, bstage, E);
    csr_kernel<<<NB2, 256, 0, stream>>>(gcur, bstage, row_be, s_iw);

    // ---- Layer 1 ----
    mfma_gemm<DIN, 0><<<gemm_grid, 256, 0, stream>>>(x, Wt1b, nullptr, hb, M);
    aggregate_kernel<<<agg_grid, 256, 0, stream>>>(hb, row_be, s_iw, agg, M);
    stats_kernel<<<1024, 256, 0, stream>>>(agg, sums, M);
    finalize_kernel<<<1, 128, 0, stream>>>(sums, g1, be1, ss);

    // ---- Layer 2 (BN1+ReLU fused into GEMM2's staged A) ----
    mfma_gemm<NHID, 1><<<gemm_grid, 256, 0, stream>>>(agg, Wt2b, ss, hb, M);
    aggregate_kernel<<<agg_grid, 256, 0, stream>>>(hb, row_be, s_iw, agg, M);
    stats_kernel<<<1024, 256, 0, stream>>>(agg, sums + 256, M);
    finalize_kernel<<<1, 128, 0, stream>>>(sums + 256, g2, be2, ss);
    apply_f32_kernel<<<app_grid, 256, 0, stream>>>(agg, ss, out, n4);
}